// Round 8
// baseline (620.513 us; speedup 1.0000x reference)
//
#include <hip/hip_runtime.h>
#include <stdint.h>

// Channel attention (Restormer MDTA style). FP32 in/out, bf16 MFMA internals.
// R12: single-variable round — gemm_tn occupancy 2 -> 3 blocks/CU via
//   __launch_bounds__(256,3) (LDS 3x48=144KB <= 160KB/CU; VGPR cap 170 >= 120
//   measured). 8 -> 12 resident waves/CU to hide the ~900cy staging waits and
//   epilogue drains that four structural rewrites could not remove at occ=16%.
//   Also: first A-frag load issued BEFORE the first __syncthreads (its L2
//   latency rides the staging drain). Everything else identical to R11.
// Pipeline per chunk of G batches:
//   gemm_tn<f32,bf16,18>: qkv_pre = Wqkv . x       (M=576)
//   dwconv2 qk    : qkv_pre ch[0,384) -> region1 bf16
//   dwconv2 v     : qkv_pre ch[384,576) -> qkv_pre ch[0,192)
//   attn_scores   : partials S/norms -> qkv_pre ch[192,..) (free region)
//   softmax_k     : attn = softmax(temp * sum(S) / (|q||k|))
//   mproj         : MmF[b] = W_proj . blockdiag(attn)  (bf16, frag layout)
//   gemm_tn<bf16,f32,6>: out = MmF . v_post        (M=192)

typedef __attribute__((ext_vector_type(8))) short bf16x8;
typedef __attribute__((ext_vector_type(4))) float f32x4;
typedef __attribute__((ext_vector_type(2))) float f32x2;
typedef __attribute__((ext_vector_type(4))) unsigned int u32x4;
typedef __attribute__((ext_vector_type(2))) unsigned int u32x2;
typedef unsigned short u16;

#define HW 16384
#define CD 192
#define O3 576
#define KD 192
#define CHWE (192LL * 16384LL)   // elements per [c][p] plane

__device__ __forceinline__ float b2f(u16 u) {
    union { unsigned int i; float f; } v; v.i = ((unsigned int)u) << 16; return v.f;
}
__device__ __forceinline__ u16 f2b(float f) {
    union { float f; unsigned int i; } v; v.f = f;
    return (u16)((v.i + 0x7fffu + ((v.i >> 16) & 1u)) >> 16);  // RNE
}

__global__ __launch_bounds__(256) void fill_f32(float* p, long long n, float val) {
    long long stride = (long long)gridDim.x * 256;
    for (long long i = blockIdx.x * 256LL + threadIdx.x; i < n; i += stride) p[i] = val;
}

// W fp32 [M][192] -> fragment-layout bf16, rows padded to NF/48*128 with zeros.
// Frag F = rwmb*24 + mt*6 + ks  (rwmb = row>>6), holds rows rwmb*64+mt*16+[0,16)
// x k ks*32+[0,32). Within frag: lane = q*16+lr, lane's 8 k at Af[F*512+lane*8].
__global__ __launch_bounds__(256) void afrag_prep(
    const float* __restrict__ W, u16* __restrict__ Af, int M, int NF)
{
    int t = blockIdx.x * 256 + threadIdx.x;
    if (t >= NF * 64) return;
    int F = t >> 6, lane = t & 63;
    int ks = F % 6, mt = (F / 6) & 3, rwmb = F / 24;
    int row = rwmb * 64 + mt * 16 + (lane & 15);
    int k0 = ks * 32 + (lane >> 4) * 8;
    u16 v[8] __attribute__((aligned(16)));
    if (row < M) {
        const float* src = W + (long long)row * KD + k0;
#pragma unroll
        for (int j = 0; j < 8; j++) v[j] = f2b(src[j]);
    } else {
#pragma unroll
        for (int j = 0; j < 8; j++) v[j] = 0;
    }
    *(bf16x8*)&Af[(long long)F * 512 + lane * 8] = *(const bf16x8*)v;
}

// C[b][m][n] = sum_k A[m][k]*B[k][n]. R10 structure, occupancy 3 blocks/CU.
template <bool SRC_F32, bool OUT_F32, int NMS>
__global__ __launch_bounds__(256, 3) void gemm_tn(
    const u16* __restrict__ Afrag, const void* __restrict__ Bsrc, void* __restrict__ Cv,
    long long af_bs, long long b_bs, long long c_bs)
{
    __shared__ u16 lsB[128 * 192];  // 48 KiB: row n (384B) = 24 slots of 16B
    const int tid = threadIdx.x, lane = tid & 63, wid = tid >> 6;
    const int n0 = blockIdx.x * 128;
    const long long bz = blockIdx.z;
    const int lr = lane & 15, quad = lane >> 4;
    const int wn = wid & 1, wm = wid >> 1;

    const u16* ApBase = Afrag + bz * af_bs + lane * 8;
    constexpr int NT = NMS / 2;  // m-steps per wave
#define LOAD_AF(dst, sv) do { \
    _Pragma("unroll") for (int mtl_ = 0; mtl_ < 2; mtl_++) \
    _Pragma("unroll") for (int ks_ = 0; ks_ < 6; ks_++) \
        dst[mtl_][ks_] = *(const bf16x8*)(ApBase + \
            (long long)(((sv) >> 1) * 24 + (((sv) & 1) * 2 + mtl_) * 6 + ks_) * 512); \
} while (0)

#define LADDR(n_, ks_) ((n_) * 192 + (((ks_) ^ (((n_) >> 2) & 7)) * 8))

    if (SRC_F32) {
        const int c32 = lane & 31, rs = lane >> 5;
        const float* gp = (const float*)Bsrc + bz * b_bs + n0 + 4 * c32;
        f32x4 bufA[8], bufB[8];
#define LOADC_F(buf, c) do { \
    const float* p_ = gp + (long long)((c) * 64 + wid * 16 + rs * 8) * HW; \
    _Pragma("unroll") for (int i_ = 0; i_ < 8; i_++) \
        buf[i_] = *(const f32x4*)(p_ + (long long)i_ * HW); \
} while (0)
#define PROC_F(buf, c) do { \
    const int kslot_ = (c) * 8 + wid * 2 + rs; \
    _Pragma("unroll") for (int j_ = 0; j_ < 4; j_++) { \
        const int n_ = 4 * c32 + j_; \
        unsigned int p0_, p1_, p2_, p3_; \
        asm("v_cvt_pk_bf16_f32 %0, %1, %2" : "=v"(p0_) : "v"(buf[0][j_]), "v"(buf[1][j_])); \
        asm("v_cvt_pk_bf16_f32 %0, %1, %2" : "=v"(p1_) : "v"(buf[2][j_]), "v"(buf[3][j_])); \
        asm("v_cvt_pk_bf16_f32 %0, %1, %2" : "=v"(p2_) : "v"(buf[4][j_]), "v"(buf[5][j_])); \
        asm("v_cvt_pk_bf16_f32 %0, %1, %2" : "=v"(p3_) : "v"(buf[6][j_]), "v"(buf[7][j_])); \
        *(u32x4*)&lsB[LADDR(n_, kslot_)] = (u32x4){p0_, p1_, p2_, p3_}; \
    } \
} while (0)
        LOADC_F(bufA, 0);
        LOADC_F(bufB, 1);
        __builtin_amdgcn_sched_barrier(0);
        PROC_F(bufA, 0);
        LOADC_F(bufA, 2);
        __builtin_amdgcn_sched_barrier(0);
        PROC_F(bufB, 1);
        PROC_F(bufA, 2);
#undef LOADC_F
#undef PROC_F
    } else {
        const int c16 = lane & 15, rs4 = lane >> 4;
        const u16* gp = (const u16*)Bsrc + bz * b_bs + n0 + 8 * c16;
        u32x4 bufA[4], bufB[4];
#define LOADC_B(buf, c) do { \
    const u16* p_ = gp + (long long)((c) * 64 + wid * 16 + rs4 * 4) * HW; \
    _Pragma("unroll") for (int i_ = 0; i_ < 4; i_++) \
        buf[i_] = *(const u32x4*)(p_ + (long long)i_ * HW); \
} while (0)
#define PROC_B(buf, c) do { \
    const int kslot_ = (c) * 8 + wid * 2 + (rs4 >> 1); \
    const int kh_ = (rs4 & 1) * 4; \
    _Pragma("unroll") for (int j_ = 0; j_ < 4; j_++) { \
        unsigned int l0_ = __builtin_amdgcn_perm(buf[0][j_], buf[1][j_], 0x01000504u); \
        unsigned int l1_ = __builtin_amdgcn_perm(buf[2][j_], buf[3][j_], 0x01000504u); \
        unsigned int h0_ = __builtin_amdgcn_perm(buf[0][j_], buf[1][j_], 0x03020706u); \
        unsigned int h1_ = __builtin_amdgcn_perm(buf[2][j_], buf[3][j_], 0x03020706u); \
        *(u32x2*)&lsB[LADDR(8 * c16 + 2 * j_, kslot_) + kh_] = (u32x2){l0_, l1_}; \
        *(u32x2*)&lsB[LADDR(8 * c16 + 2 * j_ + 1, kslot_) + kh_] = (u32x2){h0_, h1_}; \
    } \
} while (0)
        LOADC_B(bufA, 0);
        LOADC_B(bufB, 1);
        __builtin_amdgcn_sched_barrier(0);
        PROC_B(bufA, 0);
        LOADC_B(bufA, 2);
        __builtin_amdgcn_sched_barrier(0);
        PROC_B(bufB, 1);
        PROC_B(bufA, 2);
#undef LOADC_B
#undef PROC_B
    }

    // First A-frag load in flight across the staging drain.
    bf16x8 afA[2][6], afB[2][6];
    const int s0 = wm * NT;
    LOAD_AF(afA, s0);

    __syncthreads();  // LDS ready

    // ---- hoist B-frags to registers ONCE ----
    bf16x8 bfv[6][4];
#pragma unroll
    for (int ks = 0; ks < 6; ks++)
#pragma unroll
        for (int nt = 0; nt < 4; nt++) {
            const int n_ = wn * 64 + nt * 16 + lr;
            bfv[ks][nt] = *(const bf16x8*)&lsB[LADDR(n_, ks * 4 + quad)];
        }
#undef LADDR
    __syncthreads();  // all hoists done; LDS now per-wave epilogue slices

    const long long cB = bz * c_bs + n0 + wn * 64;  // wave's C col base

#define COMPUTE_MB(afb, sv) do { \
    f32x4 acc_[2][4]; \
    _Pragma("unroll") for (int i_ = 0; i_ < 2; i_++) \
    _Pragma("unroll") for (int j_ = 0; j_ < 4; j_++) \
        acc_[i_][j_] = (f32x4){0.f, 0.f, 0.f, 0.f}; \
    _Pragma("unroll") for (int ks_ = 0; ks_ < 6; ks_++) \
    _Pragma("unroll") for (int mtl_ = 0; mtl_ < 2; mtl_++) \
    _Pragma("unroll") for (int nt_ = 0; nt_ < 4; nt_++) \
        acc_[mtl_][nt_] = __builtin_amdgcn_mfma_f32_16x16x32_bf16( \
            afb[mtl_][ks_], bfv[ks_][nt_], acc_[mtl_][nt_], 0, 0, 0); \
    /* LDS-bounce epilogue: acc tile (32 rows x 64 cols) -> dense stores */ \
    if (OUT_F32) { \
        float* sl_ = (float*)lsB + wid * 2304;  /* 32*72 f32 = 9216B/wave */ \
        _Pragma("unroll") for (int mtl_ = 0; mtl_ < 2; mtl_++) \
        _Pragma("unroll") for (int r_ = 0; r_ < 4; r_++) { \
            const int row_ = mtl_ * 16 + quad * 4 + r_; \
            const int qx_ = (row_ >> 2) & 3; \
            _Pragma("unroll") for (int nt_ = 0; nt_ < 4; nt_++) \
                sl_[row_ * 72 + ((nt_ ^ qx_) * 16 + lr)] = acc_[mtl_][nt_][r_]; \
        } \
        asm volatile("s_waitcnt lgkmcnt(0)" ::: "memory"); \
        __builtin_amdgcn_sched_barrier(0); \
        _Pragma("unroll") for (int p_ = 0; p_ < 8; p_++) { \
            const int rr_ = (lane >> 4) + 4 * p_; \
            const int c4_ = (lane & 15) * 4; \
            const int pc_ = (((c4_ >> 4) ^ ((rr_ >> 2) & 3)) * 16) + (c4_ & 15); \
            f32x4 v_ = *(const f32x4*)&sl_[rr_ * 72 + pc_]; \
            *(f32x4*)&((float*)Cv)[cB + (long long)(32 * (sv) + rr_) * HW + c4_] = v_; \
        } \
    } else { \
        u16* sl_ = lsB + wid * 2304;  /* 32*72 u16 = 4608B/wave */ \
        _Pragma("unroll") for (int mtl_ = 0; mtl_ < 2; mtl_++) \
        _Pragma("unroll") for (int r_ = 0; r_ < 4; r_++) { \
            const int row_ = mtl_ * 16 + quad * 4 + r_; \
            const int qx_ = (row_ >> 2) & 3; \
            _Pragma("unroll") for (int nt_ = 0; nt_ < 4; nt_++) \
                sl_[row_ * 72 + ((nt_ ^ qx_) * 16 + lr)] = f2b(acc_[mtl_][nt_][r_]); \
        } \
        asm volatile("s_waitcnt lgkmcnt(0)" ::: "memory"); \
        __builtin_amdgcn_sched_barrier(0); \
        _Pragma("unroll") for (int p_ = 0; p_ < 4; p_++) { \
            const int rr_ = (lane >> 3) + 8 * p_; \
            const int c8_ = (lane & 7) * 8; \
            const int pc_ = (((c8_ >> 4) ^ ((rr_ >> 2) & 3)) * 16) + (c8_ & 15); \
            bf16x8 v_ = *(const bf16x8*)&sl_[rr_ * 72 + pc_]; \
            *(bf16x8*)&((u16*)Cv)[cB + (long long)(32 * (sv) + rr_) * HW + c8_] = v_; \
        } \
    } \
} while (0)

#pragma unroll
    for (int t = 0; t < NT; ++t) {
        if (t + 1 < NT) {
            if (t & 1) LOAD_AF(afA, s0 + t + 1);
            else       LOAD_AF(afB, s0 + t + 1);
            __builtin_amdgcn_sched_barrier(0);  // keep prefetch ahead of MFMAs
        }
        if (t & 1) COMPUTE_MB(afB, s0 + t);
        else       COMPUTE_MB(afA, s0 + t);
    }
#undef LOAD_AF
#undef COMPUTE_MB
}

// depthwise 3x3 SAME; in/out bf16, weights fp32 (weight row = wch0 + ch).
// 64-row tiles — halo 3%, 32 outputs/thread (4 rows x 8 cols).
__global__ __launch_bounds__(256) void dwconv2(
    const u16* __restrict__ in, const float* __restrict__ wdw, u16* __restrict__ outp,
    long long in_bs, long long out_bs, int wch0)
{
    const int rt = blockIdx.x, ch = blockIdx.y, tid = threadIdx.x;
    const long long bz = blockIdx.z;
    const u16* ip = in + bz * in_bs + (long long)ch * HW;
    u16* op = outp + bz * out_bs + (long long)ch * HW;
    __shared__ float t[66 * 132];
    const int r0 = rt * 64;
    if (tid < 66) {
        t[tid * 132 + 0] = 0.f;   t[tid * 132 + 129] = 0.f;
        t[tid * 132 + 130] = 0.f; t[tid * 132 + 131] = 0.f;
    }
    for (int i = tid; i < 1056; i += 256) {
        int rr = i >> 4, cc = (i & 15) * 8;
        int gr = r0 + rr - 1;
        float f[8];
        if (gr >= 0 && gr < 128) {
            bf16x8 v = *(const bf16x8*)(ip + gr * 128 + cc);
#pragma unroll
            for (int j = 0; j < 8; j++) f[j] = b2f((u16)v[j]);
        } else {
#pragma unroll
            for (int j = 0; j < 8; j++) f[j] = 0.f;
        }
#pragma unroll
        for (int j = 0; j < 8; j++) t[rr * 132 + 1 + cc + j] = f[j];
    }
    float w[9];
#pragma unroll
    for (int j = 0; j < 9; j++) w[j] = wdw[(wch0 + ch) * 9 + j];
    __syncthreads();
    const int rr0 = tid >> 4, c8 = (tid & 15) * 8;
#pragma unroll
    for (int j4 = 0; j4 < 4; j4++) {
        const int row = rr0 + j4 * 16;
        float o[8] = {0.f, 0.f, 0.f, 0.f, 0.f, 0.f, 0.f, 0.f};
#pragma unroll
        for (int dy = 0; dy < 3; dy++) {
            const float* rowp = &t[(row + dy) * 132 + c8];  // LDS col c8 == image col c8-1
            float r[12] __attribute__((aligned(16)));
            *(f32x4*)&r[0] = *(const f32x4*)rowp;
            *(f32x4*)&r[4] = *(const f32x4*)(rowp + 4);
            *(f32x4*)&r[8] = *(const f32x4*)(rowp + 8);
            const float w0 = w[dy * 3], w1 = w[dy * 3 + 1], w2 = w[dy * 3 + 2];
#pragma unroll
            for (int j = 0; j < 8; j++) o[j] += w0 * r[j] + w1 * r[j + 1] + w2 * r[j + 2];
        }
        u16 ob[8] __attribute__((aligned(16)));
#pragma unroll
        for (int j = 0; j < 8; j++) ob[j] = f2b(o[j]);
        *(bf16x8*)&op[(long long)(r0 + row) * 128 + c8] = *(const bf16x8*)ob;
    }
}

// Partials: per (b) slab region = qkv_pre ch[192,..) (dead after dwconv-v).
// Layout (floats, base Pb = qkv_pre + b*3*CHWE + CHWE):
//   S part:  Pb[head*36864 + kc*2304 + i]    (4 heads x 16 kc x 48x48)
//   N part:  Pb[147456 + head*1536 + kc*96 + i]  (q at [0,48), k at [48,96))
__global__ __launch_bounds__(256) void attn_scores(
    const u16* __restrict__ qk, u16* __restrict__ qkvb)
{
    const int tid = threadIdx.x, lane = tid & 63, wid = tid >> 6;
    const int kc = blockIdx.x, head = blockIdx.y;
    const long long bz = blockIdx.z;
    const u16* q = qk + bz * (2LL * CD * HW) + (long long)head * 48 * HW;
    const u16* k = q + (long long)CD * HW;
    const int lr = lane & 15, quad = lane >> 4;

    f32x4 sc[3][3], sq[3], sk[3];
#pragma unroll
    for (int i = 0; i < 3; i++) {
#pragma unroll
        for (int j = 0; j < 3; j++) sc[i][j] = (f32x4){0.f, 0.f, 0.f, 0.f};
        sq[i] = (f32x4){0.f, 0.f, 0.f, 0.f};
        sk[i] = (f32x4){0.f, 0.f, 0.f, 0.f};
    }
    const int n0 = kc * 1024 + wid * 256;
#pragma unroll 2
    for (int s = 0; s < 8; s++) {
        const int n = n0 + s * 32 + quad * 8;
        bf16x8 aq[3], ak[3];
#pragma unroll
        for (int t3 = 0; t3 < 3; t3++) {
            aq[t3] = *(const bf16x8*)(q + (long long)(t3 * 16 + lr) * HW + n);
            ak[t3] = *(const bf16x8*)(k + (long long)(t3 * 16 + lr) * HW + n);
        }
#pragma unroll
        for (int mt = 0; mt < 3; mt++)
#pragma unroll
            for (int nt = 0; nt < 3; nt++)
                sc[mt][nt] = __builtin_amdgcn_mfma_f32_16x16x32_bf16(aq[mt], ak[nt], sc[mt][nt], 0, 0, 0);
#pragma unroll
        for (int t3 = 0; t3 < 3; t3++) {
            sq[t3] = __builtin_amdgcn_mfma_f32_16x16x32_bf16(aq[t3], aq[t3], sq[t3], 0, 0, 0);
            sk[t3] = __builtin_amdgcn_mfma_f32_16x16x32_bf16(ak[t3], ak[t3], sk[t3], 0, 0, 0);
        }
    }
    __shared__ float sS[2304];
    __shared__ float snq[48], snk[48];
    for (int i = tid; i < 2304; i += 256) sS[i] = 0.f;
    if (tid < 48) { snq[tid] = 0.f; snk[tid] = 0.f; }
    __syncthreads();
#pragma unroll
    for (int mt = 0; mt < 3; mt++)
#pragma unroll
        for (int nt = 0; nt < 3; nt++)
#pragma unroll
            for (int r = 0; r < 4; r++)
                atomicAdd(&sS[(mt * 16 + quad * 4 + r) * 48 + nt * 16 + lr], sc[mt][nt][r]);
#pragma unroll
    for (int t3 = 0; t3 < 3; t3++)
#pragma unroll
        for (int r = 0; r < 4; r++) {
            int rw = quad * 4 + r;
            if (rw == lr) {
                atomicAdd(&snq[t3 * 16 + rw], sq[t3][r]);
                atomicAdd(&snk[t3 * 16 + rw], sk[t3][r]);
            }
        }
    __syncthreads();
    float* Pb = (float*)(qkvb + bz * 3 * CHWE + CHWE);
    float* Sp = Pb + head * 36864 + kc * 2304;
    float* Np = Pb + 147456 + head * 1536 + kc * 96;
    for (int i = tid; i < 2304; i += 256) Sp[i] = sS[i];
    if (tid < 48) Np[tid] = snq[tid];
    else if (tid < 96) Np[tid] = snk[tid - 48];
}

// 256 threads: cooperative coalesced sum of the 16 kc-slabs, then row softmax.
__global__ __launch_bounds__(256) void softmax_k(
    const u16* __restrict__ qkvb, const float* __restrict__ temp,
    float* __restrict__ attn, int bh0)
{
    const int tid = threadIdx.x, bx = blockIdx.x;
    const int head = bx & 3, bloc = bx >> 2;
    const int bh = bh0 + bx;
    const float* Pb = (const float*)(qkvb + (long long)bloc * 3 * CHWE + CHWE);
    const float* Sp = Pb + head * 36864;
    const float* Np = Pb + 147456 + head * 1536;
    __shared__ float Ssum[2304];
    __shared__ float Nsum[96];
    for (int i = tid; i < 2304; i += 256) {
        float s = 0.f;
#pragma unroll
        for (int kc = 0; kc < 16; kc++) s += Sp[kc * 2304 + i];
        Ssum[i] = s;
    }
    if (tid < 96) {
        float s = 0.f;
#pragma unroll
        for (int kc = 0; kc < 16; kc++) s += Np[kc * 96 + tid];
        Nsum[tid] = s;
    }
    __syncthreads();
    if (tid < 48) {
        const int r = tid;
        const float tv = temp[head];
        const float nq = fmaxf(sqrtf(Nsum[r]), 1e-12f);
        float lg[48];
        float mx = -1e30f;
#pragma unroll
        for (int d = 0; d < 48; d++) {
            float nk = fmaxf(sqrtf(Nsum[48 + d]), 1e-12f);
            float v = Ssum[r * 48 + d] * tv / (nq * nk);
            lg[d] = v; mx = fmaxf(mx, v);
        }
        float sum = 0.f;
#pragma unroll
        for (int d = 0; d < 48; d++) { float e = __expf(lg[d] - mx); lg[d] = e; sum += e; }
        const float inv = 1.f / sum;
        float* Ag = attn + (long long)bh * 2304 + r * 48;
#pragma unroll
        for (int d = 0; d < 48; d++) Ag[d] = lg[d] * inv;
    }
}

// MmF[b] = W_proj . blockdiag(attn), written directly in A-fragment layout.
__global__ __launch_bounds__(256) void mproj(
    const float* __restrict__ wproj, const float* __restrict__ attn, u16* __restrict__ Mm,
    int b0)
{
    const int ob = blockIdx.x, b = b0 + blockIdx.y, tid = threadIdx.x;
    __shared__ float sA[9216];
    const float* Ab = attn + (long long)b * 9216;
    for (int i = tid; i < 9216; i += 256) sA[i] = Ab[i];
    __syncthreads();
    for (int i = tid; i < 48 * 192; i += 256) {
        int o = ob * 48 + i / 192;
        int cc = i % 192;
        int h = cc / 48, d = cc - h * 48;
        const float* wr = wproj + o * 192 + h * 48;
        const float* ar = &sA[h * 2304 + d];
        float acc = 0.f;
        for (int c = 0; c < 48; c++) acc += wr[c] * ar[c * 48];
        // frag-layout store: F = (o>>6)*24 + ((o>>4)&3)*6 + (cc>>5)
        int fi = (o >> 6) * 24 + ((o >> 4) & 3) * 6 + (cc >> 5);
        int lanei = ((cc >> 3) & 3) * 16 + (o & 15);
        Mm[(long long)b * 49152 + (long long)fi * 512 + lanei * 8 + (cc & 7)] = f2b(acc);
    }
}

extern "C" void kernel_launch(void* const* d_in, const int* in_sizes, int n_in,
                              void* d_out, int out_size, void* d_ws, size_t ws_size,
                              hipStream_t stream)
{
    const float* x     = (const float*)d_in[0];
    const float* wqkv  = (const float*)d_in[1];
    const float* wdw   = (const float*)d_in[2];
    const float* temp  = (const float*)d_in[3];
    const float* wproj = (const float*)d_in[4];
    float* out = (float*)d_out;
    char* ws = (char*)d_ws;
    const long long CHW = CHWE;

    if (ws_size < 2097152ULL + 31457280ULL) {  // G=1 floor (proved present)
        fill_f32<<<2048, 256, 0, stream>>>(out, out_size, 100.0f);
        return;
    }
    int G = 8;
    while (G > 1 && (unsigned long long)(2097152ULL + (unsigned long long)G * 31457280ULL) > (unsigned long long)ws_size)
        G >>= 1;

    float* attn   = (float*)(ws + 307200);     // 32*2304 f32
    u16*   MmF    = (u16*)(ws + 602112);       // 8 * 96 frags * 512 u16
    u16*   wqkvF  = (u16*)(ws + 1388544);      // 240 frags * 512 u16
    u16* region1  = (u16*)(ws + 2097152);      // G*2CHW bf16 (qk_post)
    u16* qkv_pre  = region1 + (long long)G * 2 * CHW;  // G*3CHW bf16

    afrag_prep<<<60, 256, 0, stream>>>(wqkv, wqkvF, O3, 240);

    for (int g0 = 0; g0 < 8; g0 += G) {
        // qkv_pre = Wqkv . x  (B = x fp32 [c][p], transposed+cvt in staging)
        gemm_tn<true, false, 18><<<dim3(128, 1, G), 256, 0, stream>>>(
            wqkvF, x + (long long)g0 * CHW, qkv_pre, 0LL, CHW, 3LL * CHW);
        dwconv2<<<dim3(2, 384, G), 256, 0, stream>>>(
            qkv_pre, wdw, region1, 3LL * CHW, 2LL * CHW, 0);
        dwconv2<<<dim3(2, 192, G), 256, 0, stream>>>(
            qkv_pre + 2LL * CHW, wdw, qkv_pre, 3LL * CHW, 3LL * CHW, 384);
        attn_scores<<<dim3(16, 4, G), 256, 0, stream>>>(region1, qkv_pre);
        softmax_k<<<4 * G, 256, 0, stream>>>(qkv_pre, temp, attn, g0 * 4);
        mproj<<<dim3(4, G), 256, 0, stream>>>(wproj, attn, MmF, g0);
        // out = MmF . v_post  (B = qkv_pre ch[0,192) bf16 [c][p])
        gemm_tn<false, true, 6><<<dim3(128, 1, G), 256, 0, stream>>>(
            MmF + (long long)g0 * 49152, qkv_pre, out + (long long)g0 * CHW,
            49152LL, 3LL * CHW, CHW);
    }
}

// Round 9
// 389.778 us; speedup vs baseline: 1.5920x; 1.5920x over previous
//
#include <hip/hip_runtime.h>
#include <stdint.h>

// Channel attention (Restormer MDTA style). FP32 in/out, bf16 MFMA internals.
// R13: revert R12's occupancy experiment (launch_bounds(256,3) forced VGPR 84
//   -> scratch spills, FETCH 51->396MB, dur 78->246us). Back to the best-
//   measured R9 configuration ((256,2), BN=128 full-wave-row staging, direct
//   stores, R9 pipeline). ONE new lever: XCD-chunked block swizzle in gemm_tn
//   (nt = (bx%8)*16 + bx/8): adjacent n-tiles -> same XCD L2, so their
//   adjacent 256B C-row segments merge into ~4KB spans before HBM eviction
//   (targets the 2.5-3.3 TB/s effective-BW wall; fill kernel proves 6.8).
// Pipeline per chunk of G batches:
//   gemm_tn<f32,bf16,18>: qkv_pre = Wqkv . x       (M=576)
//   dwconv2 qk    : qkv_pre ch[0,384) -> region1 bf16
//   dwconv2 v     : qkv_pre ch[384,576) -> qkv_pre ch[0,192)
//   attn_scores   : S[bh] += q.k^T, norms += diag MFMA
//   softmax       : attn = softmax(temp * S / (|q||k|))
//   mproj         : MmF[b] = W_proj . blockdiag(attn)  (bf16, frag layout)
//   gemm_tn<bf16,f32,6>: out = MmF . v_post        (M=192)

typedef __attribute__((ext_vector_type(8))) short bf16x8;
typedef __attribute__((ext_vector_type(4))) float f32x4;
typedef __attribute__((ext_vector_type(2))) float f32x2;
typedef __attribute__((ext_vector_type(4))) unsigned int u32x4;
typedef __attribute__((ext_vector_type(2))) unsigned int u32x2;
typedef unsigned short u16;

#define HW 16384
#define CD 192
#define O3 576
#define KD 192

__device__ __forceinline__ float b2f(u16 u) {
    union { unsigned int i; float f; } v; v.i = ((unsigned int)u) << 16; return v.f;
}
__device__ __forceinline__ u16 f2b(float f) {
    union { float f; unsigned int i; } v; v.f = f;
    return (u16)((v.i + 0x7fffu + ((v.i >> 16) & 1u)) >> 16);  // RNE
}

__global__ __launch_bounds__(256) void fill_f32(float* p, long long n, float val) {
    long long stride = (long long)gridDim.x * 256;
    for (long long i = blockIdx.x * 256LL + threadIdx.x; i < n; i += stride) p[i] = val;
}

__global__ __launch_bounds__(256) void zerof(float* p, int n) {
    int i = blockIdx.x * 256 + threadIdx.x;
    if (i < n) p[i] = 0.f;
}

// W fp32 [M][192] -> fragment-layout bf16, rows padded to NF/48*128 with zeros.
// Frag F = rwmb*24 + mt*6 + ks  (rwmb = row>>6), holds rows rwmb*64+mt*16+[0,16)
// x k ks*32+[0,32). Within frag: lane = q*16+lr, lane's 8 k at Af[F*512+lane*8].
__global__ __launch_bounds__(256) void afrag_prep(
    const float* __restrict__ W, u16* __restrict__ Af, int M, int NF)
{
    int t = blockIdx.x * 256 + threadIdx.x;
    if (t >= NF * 64) return;
    int F = t >> 6, lane = t & 63;
    int ks = F % 6, mt = (F / 6) & 3, rwmb = F / 24;
    int row = rwmb * 64 + mt * 16 + (lane & 15);
    int k0 = ks * 32 + (lane >> 4) * 8;
    u16 v[8] __attribute__((aligned(16)));
    if (row < M) {
        const float* src = W + (long long)row * KD + k0;
#pragma unroll
        for (int j = 0; j < 8; j++) v[j] = f2b(src[j]);
    } else {
#pragma unroll
        for (int j = 0; j < 8; j++) v[j] = 0;
    }
    *(bf16x8*)&Af[(long long)F * 512 + lane * 8] = *(const bf16x8*)v;
}

// C[b][m][n] = sum_k A[m][k]*B[k][n]. B in [k][n] (row stride HW elems).
// BN=128 n-tile (XCD-chunk swizzled); staging: wave reads FULL 512B row
// segments, repack (cvt_pk / v_perm) into swizzled LDS [128n][192k]; 3 chunks
// of 64 k-rows, 2 in flight. After 1 barrier: B-frags hoisted to bfv[6][4]
// regs, waves split 2m x 2n, per-wave m-loop with double-buffered A-frag
// prefetch. NMS = total 32-row m-steps (M/32).
template <bool SRC_F32, bool OUT_F32, int NMS>
__global__ __launch_bounds__(256, 2) void gemm_tn(
    const u16* __restrict__ Afrag, const void* __restrict__ Bsrc, void* __restrict__ Cv,
    long long af_bs, long long b_bs, long long c_bs)
{
    __shared__ u16 lsB[128 * 192];  // 48 KiB: row n (384B) = 24 slots of 16B
    const int tid = threadIdx.x, lane = tid & 63, wid = tid >> 6;
    // XCD-chunked swizzle: blocks on XCD j (= bx%8) cover n-tiles [j*16,(j+1)*16)
    const int bx = blockIdx.x;
    const int n0 = (((bx & 7) << 4) + (bx >> 3)) * 128;
    const long long bz = blockIdx.z;
    const int lr = lane & 15, quad = lane >> 4;
    const int wn = wid & 1, wm = wid >> 1;

#define LADDR(n_, ks_) ((n_) * 192 + (((ks_) ^ (((n_) >> 2) & 7)) * 8))

    if (SRC_F32) {
        const int c32 = lane & 31, rs = lane >> 5;
        const float* gp = (const float*)Bsrc + bz * b_bs + n0 + 4 * c32;
        f32x4 bufA[8], bufB[8];
#define LOADC_F(buf, c) do { \
    const float* p_ = gp + (long long)((c) * 64 + wid * 16 + rs * 8) * HW; \
    _Pragma("unroll") for (int i_ = 0; i_ < 8; i_++) \
        buf[i_] = *(const f32x4*)(p_ + (long long)i_ * HW); \
} while (0)
#define PROC_F(buf, c) do { \
    const int kslot_ = (c) * 8 + wid * 2 + rs; \
    _Pragma("unroll") for (int j_ = 0; j_ < 4; j_++) { \
        const int n_ = 4 * c32 + j_; \
        unsigned int p0_, p1_, p2_, p3_; \
        asm("v_cvt_pk_bf16_f32 %0, %1, %2" : "=v"(p0_) : "v"(buf[0][j_]), "v"(buf[1][j_])); \
        asm("v_cvt_pk_bf16_f32 %0, %1, %2" : "=v"(p1_) : "v"(buf[2][j_]), "v"(buf[3][j_])); \
        asm("v_cvt_pk_bf16_f32 %0, %1, %2" : "=v"(p2_) : "v"(buf[4][j_]), "v"(buf[5][j_])); \
        asm("v_cvt_pk_bf16_f32 %0, %1, %2" : "=v"(p3_) : "v"(buf[6][j_]), "v"(buf[7][j_])); \
        *(u32x4*)&lsB[LADDR(n_, kslot_)] = (u32x4){p0_, p1_, p2_, p3_}; \
    } \
} while (0)
        LOADC_F(bufA, 0);
        LOADC_F(bufB, 1);
        __builtin_amdgcn_sched_barrier(0);
        PROC_F(bufA, 0);
        LOADC_F(bufA, 2);
        __builtin_amdgcn_sched_barrier(0);
        PROC_F(bufB, 1);
        PROC_F(bufA, 2);
#undef LOADC_F
#undef PROC_F
    } else {
        const int c16 = lane & 15, rs4 = lane >> 4;
        const u16* gp = (const u16*)Bsrc + bz * b_bs + n0 + 8 * c16;
        u32x4 bufA[4], bufB[4];
#define LOADC_B(buf, c) do { \
    const u16* p_ = gp + (long long)((c) * 64 + wid * 16 + rs4 * 4) * HW; \
    _Pragma("unroll") for (int i_ = 0; i_ < 4; i_++) \
        buf[i_] = *(const u32x4*)(p_ + (long long)i_ * HW); \
} while (0)
#define PROC_B(buf, c) do { \
    const int kslot_ = (c) * 8 + wid * 2 + (rs4 >> 1); \
    const int kh_ = (rs4 & 1) * 4; \
    _Pragma("unroll") for (int j_ = 0; j_ < 4; j_++) { \
        unsigned int l0_ = __builtin_amdgcn_perm(buf[0][j_], buf[1][j_], 0x01000504u); \
        unsigned int l1_ = __builtin_amdgcn_perm(buf[2][j_], buf[3][j_], 0x01000504u); \
        unsigned int h0_ = __builtin_amdgcn_perm(buf[0][j_], buf[1][j_], 0x03020706u); \
        unsigned int h1_ = __builtin_amdgcn_perm(buf[2][j_], buf[3][j_], 0x03020706u); \
        *(u32x2*)&lsB[LADDR(8 * c16 + 2 * j_, kslot_) + kh_] = (u32x2){l0_, l1_}; \
        *(u32x2*)&lsB[LADDR(8 * c16 + 2 * j_ + 1, kslot_) + kh_] = (u32x2){h0_, h1_}; \
    } \
} while (0)
        LOADC_B(bufA, 0);
        LOADC_B(bufB, 1);
        __builtin_amdgcn_sched_barrier(0);
        PROC_B(bufA, 0);
        LOADC_B(bufA, 2);
        __builtin_amdgcn_sched_barrier(0);
        PROC_B(bufB, 1);
        PROC_B(bufA, 2);
#undef LOADC_B
#undef PROC_B
    }
    __syncthreads();  // LDS ready; static for whole kernel

    // ---- hoist B-frags to registers ONCE (LDS dead afterwards) ----
    bf16x8 bfv[6][4];
#pragma unroll
    for (int ks = 0; ks < 6; ks++)
#pragma unroll
        for (int nt = 0; nt < 4; nt++) {
            const int n_ = wn * 64 + nt * 16 + lr;
            bfv[ks][nt] = *(const bf16x8*)&lsB[LADDR(n_, ks * 4 + quad)];
        }
#undef LADDR

    const u16* ApBase = Afrag + bz * af_bs + lane * 8;
    const long long cB = bz * c_bs + n0 + wn * 64 + lr;
    constexpr int NT = NMS / 2;  // m-steps per wave

#define LOAD_AF(dst, sv) do { \
    _Pragma("unroll") for (int mtl_ = 0; mtl_ < 2; mtl_++) \
    _Pragma("unroll") for (int ks_ = 0; ks_ < 6; ks_++) \
        dst[mtl_][ks_] = *(const bf16x8*)(ApBase + \
            (long long)(((sv) >> 1) * 24 + (((sv) & 1) * 2 + mtl_) * 6 + ks_) * 512); \
} while (0)
#define COMPUTE_MB(afb, sv) do { \
    f32x4 acc_[2][4]; \
    _Pragma("unroll") for (int i_ = 0; i_ < 2; i_++) \
    _Pragma("unroll") for (int j_ = 0; j_ < 4; j_++) \
        acc_[i_][j_] = (f32x4){0.f, 0.f, 0.f, 0.f}; \
    _Pragma("unroll") for (int ks_ = 0; ks_ < 6; ks_++) \
    _Pragma("unroll") for (int mtl_ = 0; mtl_ < 2; mtl_++) \
    _Pragma("unroll") for (int nt_ = 0; nt_ < 4; nt_++) \
        acc_[mtl_][nt_] = __builtin_amdgcn_mfma_f32_16x16x32_bf16( \
            afb[mtl_][ks_], bfv[ks_][nt_], acc_[mtl_][nt_], 0, 0, 0); \
    _Pragma("unroll") for (int mtl_ = 0; mtl_ < 2; mtl_++) \
    _Pragma("unroll") for (int r_ = 0; r_ < 4; r_++) { \
        const long long ro_ = cB + (long long)(32 * (sv) + mtl_ * 16 + quad * 4 + r_) * HW; \
        _Pragma("unroll") for (int nt_ = 0; nt_ < 4; nt_++) { \
            if (OUT_F32) ((float*)Cv)[ro_ + nt_ * 16] = acc_[mtl_][nt_][r_]; \
            else         ((u16*)Cv)[ro_ + nt_ * 16] = f2b(acc_[mtl_][nt_][r_]); \
        } \
    } \
} while (0)

    bf16x8 afA[2][6], afB[2][6];
    const int s0 = wm * NT;
    LOAD_AF(afA, s0);
#pragma unroll
    for (int t = 0; t < NT; ++t) {
        if (t + 1 < NT) {
            if (t & 1) LOAD_AF(afA, s0 + t + 1);
            else       LOAD_AF(afB, s0 + t + 1);
            __builtin_amdgcn_sched_barrier(0);  // keep prefetch ahead of MFMAs
        }
        if (t & 1) COMPUTE_MB(afB, s0 + t);
        else       COMPUTE_MB(afA, s0 + t);
    }
#undef LOAD_AF
#undef COMPUTE_MB
}

// depthwise 3x3 SAME; in/out bf16, weights fp32 (weight row = wch0 + ch).
__global__ __launch_bounds__(256) void dwconv2(
    const u16* __restrict__ in, const float* __restrict__ wdw, u16* __restrict__ outp,
    long long in_bs, long long out_bs, int wch0)
{
    const int rt = blockIdx.x, ch = blockIdx.y, tid = threadIdx.x;
    const long long bz = blockIdx.z;
    const u16* ip = in + bz * in_bs + (long long)ch * HW;
    u16* op = outp + bz * out_bs + (long long)ch * HW;
    __shared__ float t[18 * 132];
    const int r0 = rt * 16;
    if (tid < 18) {
        t[tid * 132 + 0] = 0.f;   t[tid * 132 + 129] = 0.f;
        t[tid * 132 + 130] = 0.f; t[tid * 132 + 131] = 0.f;
    }
    for (int i = tid; i < 288; i += 256) {
        int rr = i >> 4, cc = (i & 15) * 8;
        int gr = r0 + rr - 1;
        float f[8];
        if (gr >= 0 && gr < 128) {
            bf16x8 v = *(const bf16x8*)(ip + gr * 128 + cc);
#pragma unroll
            for (int j = 0; j < 8; j++) f[j] = b2f((u16)v[j]);
        } else {
#pragma unroll
            for (int j = 0; j < 8; j++) f[j] = 0.f;
        }
#pragma unroll
        for (int j = 0; j < 8; j++) t[rr * 132 + 1 + cc + j] = f[j];
    }
    float w[9];
#pragma unroll
    for (int j = 0; j < 9; j++) w[j] = wdw[(wch0 + ch) * 9 + j];
    __syncthreads();
    const int rr = tid >> 4, c8 = (tid & 15) * 8;
    float o[8] = {0.f, 0.f, 0.f, 0.f, 0.f, 0.f, 0.f, 0.f};
#pragma unroll
    for (int dy = 0; dy < 3; dy++) {
        const float* row = &t[(rr + dy) * 132 + c8];  // LDS idx c8 == image col c8-1
        float r[12] __attribute__((aligned(16)));
        *(f32x4*)&r[0] = *(const f32x4*)row;
        *(f32x4*)&r[4] = *(const f32x4*)(row + 4);
        *(f32x4*)&r[8] = *(const f32x4*)(row + 8);
        const float w0 = w[dy * 3], w1 = w[dy * 3 + 1], w2 = w[dy * 3 + 2];
#pragma unroll
        for (int j = 0; j < 8; j++) o[j] += w0 * r[j] + w1 * r[j + 1] + w2 * r[j + 2];
    }
    u16 ob[8] __attribute__((aligned(16)));
#pragma unroll
    for (int j = 0; j < 8; j++) ob[j] = f2b(o[j]);
    *(bf16x8*)&op[(long long)(r0 + rr) * 128 + c8] = *(const bf16x8*)ob;
}

// S[bh][48][48] += q.k^T ; norms[bh][96] += diag(q.q^T), diag(k.k^T)
__global__ __launch_bounds__(256) void attn_scores(
    const u16* __restrict__ qk, float* __restrict__ S, float* __restrict__ norms,
    int bh0)
{
    const int tid = threadIdx.x, lane = tid & 63, wid = tid >> 6;
    const int kc = blockIdx.x, head = blockIdx.y;
    const long long bz = blockIdx.z;
    const u16* q = qk + bz * (2LL * CD * HW) + (long long)head * 48 * HW;
    const u16* k = q + (long long)CD * HW;
    const int lr = lane & 15, quad = lane >> 4;

    f32x4 sc[3][3], sq[3], sk[3];
#pragma unroll
    for (int i = 0; i < 3; i++) {
#pragma unroll
        for (int j = 0; j < 3; j++) sc[i][j] = (f32x4){0.f, 0.f, 0.f, 0.f};
        sq[i] = (f32x4){0.f, 0.f, 0.f, 0.f};
        sk[i] = (f32x4){0.f, 0.f, 0.f, 0.f};
    }
    const int n0 = kc * 1024 + wid * 256;
#pragma unroll 2
    for (int s = 0; s < 8; s++) {
        const int n = n0 + s * 32 + quad * 8;
        bf16x8 aq[3], ak[3];
#pragma unroll
        for (int t3 = 0; t3 < 3; t3++) {
            aq[t3] = *(const bf16x8*)(q + (long long)(t3 * 16 + lr) * HW + n);
            ak[t3] = *(const bf16x8*)(k + (long long)(t3 * 16 + lr) * HW + n);
        }
#pragma unroll
        for (int mt = 0; mt < 3; mt++)
#pragma unroll
            for (int nt = 0; nt < 3; nt++)
                sc[mt][nt] = __builtin_amdgcn_mfma_f32_16x16x32_bf16(aq[mt], ak[nt], sc[mt][nt], 0, 0, 0);
#pragma unroll
        for (int t3 = 0; t3 < 3; t3++) {
            sq[t3] = __builtin_amdgcn_mfma_f32_16x16x32_bf16(aq[t3], aq[t3], sq[t3], 0, 0, 0);
            sk[t3] = __builtin_amdgcn_mfma_f32_16x16x32_bf16(ak[t3], ak[t3], sk[t3], 0, 0, 0);
        }
    }
    __shared__ float sS[2304];
    __shared__ float snq[48], snk[48];
    for (int i = tid; i < 2304; i += 256) sS[i] = 0.f;
    if (tid < 48) { snq[tid] = 0.f; snk[tid] = 0.f; }
    __syncthreads();
#pragma unroll
    for (int mt = 0; mt < 3; mt++)
#pragma unroll
        for (int nt = 0; nt < 3; nt++)
#pragma unroll
            for (int r = 0; r < 4; r++)
                atomicAdd(&sS[(mt * 16 + quad * 4 + r) * 48 + nt * 16 + lr], sc[mt][nt][r]);
#pragma unroll
    for (int t3 = 0; t3 < 3; t3++)
#pragma unroll
        for (int r = 0; r < 4; r++) {
            int rw = quad * 4 + r;
            if (rw == lr) {
                atomicAdd(&snq[t3 * 16 + rw], sq[t3][r]);
                atomicAdd(&snk[t3 * 16 + rw], sk[t3][r]);
            }
        }
    __syncthreads();
    const int bh = bh0 + (int)bz * 4 + head;
    float* Sg = S + (long long)bh * 2304;
    for (int i = tid; i < 2304; i += 256) atomicAdd(&Sg[i], sS[i]);
    float* ng = norms + bh * 96;
    if (tid < 48) atomicAdd(&ng[tid], snq[tid]);
    else if (tid < 96) atomicAdd(&ng[tid], snk[tid - 48]);
}

__global__ __launch_bounds__(64) void softmax_k(
    const float* __restrict__ S, const float* __restrict__ norms,
    const float* __restrict__ temp, float* __restrict__ attn, int bh0)
{
    const int bh = bh0 + blockIdx.x, head = bh & 3, r = threadIdx.x;
    if (r >= 48) return;
    const float tv = temp[head];
    const float* Sg = S + (long long)bh * 2304;
    const float* ng = norms + bh * 96;
    const float nq = fmaxf(sqrtf(ng[r]), 1e-12f);
    float lg[48];
    float mx = -1e30f;
#pragma unroll
    for (int d = 0; d < 48; d++) {
        float nk = fmaxf(sqrtf(ng[48 + d]), 1e-12f);
        float v = Sg[r * 48 + d] * tv / (nq * nk);
        lg[d] = v; mx = fmaxf(mx, v);
    }
    float sum = 0.f;
#pragma unroll
    for (int d = 0; d < 48; d++) { float e = __expf(lg[d] - mx); lg[d] = e; sum += e; }
    const float inv = 1.f / sum;
    float* Ag = attn + (long long)bh * 2304 + r * 48;
#pragma unroll
    for (int d = 0; d < 48; d++) Ag[d] = lg[d] * inv;
}

// MmF[b] = W_proj . blockdiag(attn), written directly in A-fragment layout.
__global__ __launch_bounds__(256) void mproj(
    const float* __restrict__ wproj, const float* __restrict__ attn, u16* __restrict__ Mm,
    int b0)
{
    const int ob = blockIdx.x, b = b0 + blockIdx.y, tid = threadIdx.x;
    __shared__ float sA[9216];
    const float* Ab = attn + (long long)b * 9216;
    for (int i = tid; i < 9216; i += 256) sA[i] = Ab[i];
    __syncthreads();
    for (int i = tid; i < 48 * 192; i += 256) {
        int o = ob * 48 + i / 192;
        int cc = i % 192;
        int h = cc / 48, d = cc - h * 48;
        const float* wr = wproj + o * 192 + h * 48;
        const float* ar = &sA[h * 2304 + d];
        float acc = 0.f;
        for (int c = 0; c < 48; c++) acc += wr[c] * ar[c * 48];
        // frag-layout store: F = (o>>6)*24 + ((o>>4)&3)*6 + (cc>>5)
        int fi = (o >> 6) * 24 + ((o >> 4) & 3) * 6 + (cc >> 5);
        int lanei = ((cc >> 3) & 3) * 16 + (o & 15);
        Mm[(long long)b * 49152 + (long long)fi * 512 + lanei * 8 + (cc & 7)] = f2b(acc);
    }
}

extern "C" void kernel_launch(void* const* d_in, const int* in_sizes, int n_in,
                              void* d_out, int out_size, void* d_ws, size_t ws_size,
                              hipStream_t stream)
{
    const float* x     = (const float*)d_in[0];
    const float* wqkv  = (const float*)d_in[1];
    const float* wdw   = (const float*)d_in[2];
    const float* temp  = (const float*)d_in[3];
    const float* wproj = (const float*)d_in[4];
    float* out = (float*)d_out;
    char* ws = (char*)d_ws;
    const long long CHW = (long long)CD * HW;

    if (ws_size < 2097152ULL + 31457280ULL) {  // G=1 floor (proved present)
        fill_f32<<<2048, 256, 0, stream>>>(out, out_size, 100.0f);
        return;
    }
    int G = 8;
    while (G > 1 && (unsigned long long)(2097152ULL + (unsigned long long)G * 31457280ULL) > (unsigned long long)ws_size)
        G >>= 1;

    float* S      = (float*)ws;                // 32*2304 f32
    float* norms  = (float*)(ws + 294912);     // 32*96 f32
    float* attn   = (float*)(ws + 307200);     // 32*2304 f32
    u16*   MmF    = (u16*)(ws + 602112);       // 8 * 96 frags * 512 u16
    u16*   wqkvF  = (u16*)(ws + 1388544);      // 240 frags * 512 u16
    u16* region1  = (u16*)(ws + 2097152);      // G*2CHW bf16 (qk_post)
    u16* qkv_pre  = region1 + (long long)G * 2 * CHW;  // G*3CHW bf16

    zerof<<<300, 256, 0, stream>>>(S, 76800);  // S + norms contiguous
    afrag_prep<<<60, 256, 0, stream>>>(wqkv, wqkvF, O3, 240);

    for (int g0 = 0; g0 < 8; g0 += G) {
        // qkv_pre = Wqkv . x  (B = x fp32 [c][p], transposed+cvt in staging)
        gemm_tn<true, false, 18><<<dim3(128, 1, G), 256, 0, stream>>>(
            wqkvF, x + (long long)g0 * CHW, qkv_pre, 0LL, CHW, 3LL * CHW);
        dwconv2<<<dim3(8, 384, G), 256, 0, stream>>>(
            qkv_pre, wdw, region1, 3LL * CHW, 2LL * CHW, 0);
        dwconv2<<<dim3(8, 192, G), 256, 0, stream>>>(
            qkv_pre + 2LL * CHW, wdw, qkv_pre, 3LL * CHW, 3LL * CHW, 384);
        attn_scores<<<dim3(16, 4, G), 256, 0, stream>>>(region1, S, norms, g0 * 4);
        softmax_k<<<4 * G, 64, 0, stream>>>(S, norms, temp, attn, g0 * 4);
        mproj<<<dim3(4, G), 256, 0, stream>>>(wproj, attn, MmF, g0);
        // out = MmF . v_post  (B = qkv_pre ch[0,192) bf16 [c][p])
        gemm_tn<false, true, 6><<<dim3(128, 1, G), 256, 0, stream>>>(
            MmF + (long long)g0 * 49152, qkv_pre, out + (long long)g0 * CHW,
            49152LL, 3LL * CHW, CHW);
    }
}

// Round 10
// 386.344 us; speedup vs baseline: 1.6061x; 1.0089x over previous
//
#include <hip/hip_runtime.h>
#include <stdint.h>

// Channel attention (Restormer MDTA style). FP32 in/out, bf16 MFMA internals.
// R14: consolidation. (1) Revert R13's XCD swizzle — it HURT (gemm1 78->103us,
//   BW 2.5->2.0 TB/s): default round-robin block->XCD already spreads traffic
//   across all HBM channels; chunking serialized each XCD's channel footprint.
//   (2) softmax fused into mproj (mproj_sm): softmax_k was a separate launch
//   whose 294KB output round-tripped global just to be re-read by mproj. Each
//   mproj block now computes its batch's full 192-row softmax from S/norms
//   into the LDS buffer it already stages (tid<192, 1 row/thread; 4 blocks/
//   batch redundantly — cheap), killing one kernel + gap + the attn buffer.
//   gemm_tn / staging / frag layout = measured-best R9 exactly.
// Pipeline per chunk of G batches:
//   gemm_tn<f32,bf16,18>: qkv_pre = Wqkv . x       (M=576)
//   dwconv2 qk    : qkv_pre ch[0,384) -> region1 bf16
//   dwconv2 v     : qkv_pre ch[384,576) -> qkv_pre ch[0,192)
//   attn_scores   : S[bh] += q.k^T, norms += diag MFMA
//   mproj_sm      : softmax(S) in-LDS -> MmF[b] = W_proj . blockdiag(attn)
//   gemm_tn<bf16,f32,6>: out = MmF . v_post        (M=192)

typedef __attribute__((ext_vector_type(8))) short bf16x8;
typedef __attribute__((ext_vector_type(4))) float f32x4;
typedef __attribute__((ext_vector_type(2))) float f32x2;
typedef __attribute__((ext_vector_type(4))) unsigned int u32x4;
typedef __attribute__((ext_vector_type(2))) unsigned int u32x2;
typedef unsigned short u16;

#define HW 16384
#define CD 192
#define O3 576
#define KD 192

__device__ __forceinline__ float b2f(u16 u) {
    union { unsigned int i; float f; } v; v.i = ((unsigned int)u) << 16; return v.f;
}
__device__ __forceinline__ u16 f2b(float f) {
    union { float f; unsigned int i; } v; v.f = f;
    return (u16)((v.i + 0x7fffu + ((v.i >> 16) & 1u)) >> 16);  // RNE
}

__global__ __launch_bounds__(256) void fill_f32(float* p, long long n, float val) {
    long long stride = (long long)gridDim.x * 256;
    for (long long i = blockIdx.x * 256LL + threadIdx.x; i < n; i += stride) p[i] = val;
}

__global__ __launch_bounds__(256) void zerof(float* p, int n) {
    int i = blockIdx.x * 256 + threadIdx.x;
    if (i < n) p[i] = 0.f;
}

// W fp32 [M][192] -> fragment-layout bf16, rows padded to NF/48*128 with zeros.
// Frag F = rwmb*24 + mt*6 + ks  (rwmb = row>>6), holds rows rwmb*64+mt*16+[0,16)
// x k ks*32+[0,32). Within frag: lane = q*16+lr, lane's 8 k at Af[F*512+lane*8].
__global__ __launch_bounds__(256) void afrag_prep(
    const float* __restrict__ W, u16* __restrict__ Af, int M, int NF)
{
    int t = blockIdx.x * 256 + threadIdx.x;
    if (t >= NF * 64) return;
    int F = t >> 6, lane = t & 63;
    int ks = F % 6, mt = (F / 6) & 3, rwmb = F / 24;
    int row = rwmb * 64 + mt * 16 + (lane & 15);
    int k0 = ks * 32 + (lane >> 4) * 8;
    u16 v[8] __attribute__((aligned(16)));
    if (row < M) {
        const float* src = W + (long long)row * KD + k0;
#pragma unroll
        for (int j = 0; j < 8; j++) v[j] = f2b(src[j]);
    } else {
#pragma unroll
        for (int j = 0; j < 8; j++) v[j] = 0;
    }
    *(bf16x8*)&Af[(long long)F * 512 + lane * 8] = *(const bf16x8*)v;
}

// C[b][m][n] = sum_k A[m][k]*B[k][n]. B in [k][n] (row stride HW elems).
// BN=128 n-tile; staging: wave reads FULL 512B row segments, repack
// (cvt_pk / v_perm) into swizzled LDS [128n][192k]; 3 chunks of 64 k-rows,
// 2 in flight. After 1 barrier: B-frags via LDS reads, waves split 2m x 2n,
// per-wave m-loop with double-buffered A-frag prefetch. NMS = M/32 m-steps.
template <bool SRC_F32, bool OUT_F32, int NMS>
__global__ __launch_bounds__(256, 2) void gemm_tn(
    const u16* __restrict__ Afrag, const void* __restrict__ Bsrc, void* __restrict__ Cv,
    long long af_bs, long long b_bs, long long c_bs)
{
    __shared__ u16 lsB[128 * 192];  // 48 KiB: row n (384B) = 24 slots of 16B
    const int tid = threadIdx.x, lane = tid & 63, wid = tid >> 6;
    const int n0 = blockIdx.x * 128;
    const long long bz = blockIdx.z;
    const int lr = lane & 15, quad = lane >> 4;
    const int wn = wid & 1, wm = wid >> 1;

#define LADDR(n_, ks_) ((n_) * 192 + (((ks_) ^ (((n_) >> 2) & 7)) * 8))

    if (SRC_F32) {
        const int c32 = lane & 31, rs = lane >> 5;
        const float* gp = (const float*)Bsrc + bz * b_bs + n0 + 4 * c32;
        f32x4 bufA[8], bufB[8];
#define LOADC_F(buf, c) do { \
    const float* p_ = gp + (long long)((c) * 64 + wid * 16 + rs * 8) * HW; \
    _Pragma("unroll") for (int i_ = 0; i_ < 8; i_++) \
        buf[i_] = *(const f32x4*)(p_ + (long long)i_ * HW); \
} while (0)
#define PROC_F(buf, c) do { \
    const int kslot_ = (c) * 8 + wid * 2 + rs; \
    _Pragma("unroll") for (int j_ = 0; j_ < 4; j_++) { \
        const int n_ = 4 * c32 + j_; \
        unsigned int p0_, p1_, p2_, p3_; \
        asm("v_cvt_pk_bf16_f32 %0, %1, %2" : "=v"(p0_) : "v"(buf[0][j_]), "v"(buf[1][j_])); \
        asm("v_cvt_pk_bf16_f32 %0, %1, %2" : "=v"(p1_) : "v"(buf[2][j_]), "v"(buf[3][j_])); \
        asm("v_cvt_pk_bf16_f32 %0, %1, %2" : "=v"(p2_) : "v"(buf[4][j_]), "v"(buf[5][j_])); \
        asm("v_cvt_pk_bf16_f32 %0, %1, %2" : "=v"(p3_) : "v"(buf[6][j_]), "v"(buf[7][j_])); \
        *(u32x4*)&lsB[LADDR(n_, kslot_)] = (u32x4){p0_, p1_, p2_, p3_}; \
    } \
} while (0)
        LOADC_F(bufA, 0);
        LOADC_F(bufB, 1);
        __builtin_amdgcn_sched_barrier(0);
        PROC_F(bufA, 0);
        LOADC_F(bufA, 2);
        __builtin_amdgcn_sched_barrier(0);
        PROC_F(bufB, 1);
        PROC_F(bufA, 2);
#undef LOADC_F
#undef PROC_F
    } else {
        const int c16 = lane & 15, rs4 = lane >> 4;
        const u16* gp = (const u16*)Bsrc + bz * b_bs + n0 + 8 * c16;
        u32x4 bufA[4], bufB[4];
#define LOADC_B(buf, c) do { \
    const u16* p_ = gp + (long long)((c) * 64 + wid * 16 + rs4 * 4) * HW; \
    _Pragma("unroll") for (int i_ = 0; i_ < 4; i_++) \
        buf[i_] = *(const u32x4*)(p_ + (long long)i_ * HW); \
} while (0)
#define PROC_B(buf, c) do { \
    const int kslot_ = (c) * 8 + wid * 2 + (rs4 >> 1); \
    const int kh_ = (rs4 & 1) * 4; \
    _Pragma("unroll") for (int j_ = 0; j_ < 4; j_++) { \
        unsigned int l0_ = __builtin_amdgcn_perm(buf[0][j_], buf[1][j_], 0x01000504u); \
        unsigned int l1_ = __builtin_amdgcn_perm(buf[2][j_], buf[3][j_], 0x01000504u); \
        unsigned int h0_ = __builtin_amdgcn_perm(buf[0][j_], buf[1][j_], 0x03020706u); \
        unsigned int h1_ = __builtin_amdgcn_perm(buf[2][j_], buf[3][j_], 0x03020706u); \
        *(u32x2*)&lsB[LADDR(8 * c16 + 2 * j_, kslot_) + kh_] = (u32x2){l0_, l1_}; \
        *(u32x2*)&lsB[LADDR(8 * c16 + 2 * j_ + 1, kslot_) + kh_] = (u32x2){h0_, h1_}; \
    } \
} while (0)
        LOADC_B(bufA, 0);
        LOADC_B(bufB, 1);
        __builtin_amdgcn_sched_barrier(0);
        PROC_B(bufA, 0);
        LOADC_B(bufA, 2);
        __builtin_amdgcn_sched_barrier(0);
        PROC_B(bufB, 1);
        PROC_B(bufA, 2);
#undef LOADC_B
#undef PROC_B
    }
    __syncthreads();  // LDS ready; static for whole kernel

    // ---- B-frag access (compiler keeps these as LDS reads per m-step) ----
    bf16x8 bfv[6][4];
#pragma unroll
    for (int ks = 0; ks < 6; ks++)
#pragma unroll
        for (int nt = 0; nt < 4; nt++) {
            const int n_ = wn * 64 + nt * 16 + lr;
            bfv[ks][nt] = *(const bf16x8*)&lsB[LADDR(n_, ks * 4 + quad)];
        }
#undef LADDR

    const u16* ApBase = Afrag + bz * af_bs + lane * 8;
    const long long cB = bz * c_bs + n0 + wn * 64 + lr;
    constexpr int NT = NMS / 2;  // m-steps per wave

#define LOAD_AF(dst, sv) do { \
    _Pragma("unroll") for (int mtl_ = 0; mtl_ < 2; mtl_++) \
    _Pragma("unroll") for (int ks_ = 0; ks_ < 6; ks_++) \
        dst[mtl_][ks_] = *(const bf16x8*)(ApBase + \
            (long long)(((sv) >> 1) * 24 + (((sv) & 1) * 2 + mtl_) * 6 + ks_) * 512); \
} while (0)
#define COMPUTE_MB(afb, sv) do { \
    f32x4 acc_[2][4]; \
    _Pragma("unroll") for (int i_ = 0; i_ < 2; i_++) \
    _Pragma("unroll") for (int j_ = 0; j_ < 4; j_++) \
        acc_[i_][j_] = (f32x4){0.f, 0.f, 0.f, 0.f}; \
    _Pragma("unroll") for (int ks_ = 0; ks_ < 6; ks_++) \
    _Pragma("unroll") for (int mtl_ = 0; mtl_ < 2; mtl_++) \
    _Pragma("unroll") for (int nt_ = 0; nt_ < 4; nt_++) \
        acc_[mtl_][nt_] = __builtin_amdgcn_mfma_f32_16x16x32_bf16( \
            afb[mtl_][ks_], bfv[ks_][nt_], acc_[mtl_][nt_], 0, 0, 0); \
    _Pragma("unroll") for (int mtl_ = 0; mtl_ < 2; mtl_++) \
    _Pragma("unroll") for (int r_ = 0; r_ < 4; r_++) { \
        const long long ro_ = cB + (long long)(32 * (sv) + mtl_ * 16 + quad * 4 + r_) * HW; \
        _Pragma("unroll") for (int nt_ = 0; nt_ < 4; nt_++) { \
            if (OUT_F32) ((float*)Cv)[ro_ + nt_ * 16] = acc_[mtl_][nt_][r_]; \
            else         ((u16*)Cv)[ro_ + nt_ * 16] = f2b(acc_[mtl_][nt_][r_]); \
        } \
    } \
} while (0)

    bf16x8 afA[2][6], afB[2][6];
    const int s0 = wm * NT;
    LOAD_AF(afA, s0);
#pragma unroll
    for (int t = 0; t < NT; ++t) {
        if (t + 1 < NT) {
            if (t & 1) LOAD_AF(afA, s0 + t + 1);
            else       LOAD_AF(afB, s0 + t + 1);
            __builtin_amdgcn_sched_barrier(0);  // keep prefetch ahead of MFMAs
        }
        if (t & 1) COMPUTE_MB(afB, s0 + t);
        else       COMPUTE_MB(afA, s0 + t);
    }
#undef LOAD_AF
#undef COMPUTE_MB
}

// depthwise 3x3 SAME; in/out bf16, weights fp32 (weight row = wch0 + ch).
__global__ __launch_bounds__(256) void dwconv2(
    const u16* __restrict__ in, const float* __restrict__ wdw, u16* __restrict__ outp,
    long long in_bs, long long out_bs, int wch0)
{
    const int rt = blockIdx.x, ch = blockIdx.y, tid = threadIdx.x;
    const long long bz = blockIdx.z;
    const u16* ip = in + bz * in_bs + (long long)ch * HW;
    u16* op = outp + bz * out_bs + (long long)ch * HW;
    __shared__ float t[18 * 132];
    const int r0 = rt * 16;
    if (tid < 18) {
        t[tid * 132 + 0] = 0.f;   t[tid * 132 + 129] = 0.f;
        t[tid * 132 + 130] = 0.f; t[tid * 132 + 131] = 0.f;
    }
    for (int i = tid; i < 288; i += 256) {
        int rr = i >> 4, cc = (i & 15) * 8;
        int gr = r0 + rr - 1;
        float f[8];
        if (gr >= 0 && gr < 128) {
            bf16x8 v = *(const bf16x8*)(ip + gr * 128 + cc);
#pragma unroll
            for (int j = 0; j < 8; j++) f[j] = b2f((u16)v[j]);
        } else {
#pragma unroll
            for (int j = 0; j < 8; j++) f[j] = 0.f;
        }
#pragma unroll
        for (int j = 0; j < 8; j++) t[rr * 132 + 1 + cc + j] = f[j];
    }
    float w[9];
#pragma unroll
    for (int j = 0; j < 9; j++) w[j] = wdw[(wch0 + ch) * 9 + j];
    __syncthreads();
    const int rr = tid >> 4, c8 = (tid & 15) * 8;
    float o[8] = {0.f, 0.f, 0.f, 0.f, 0.f, 0.f, 0.f, 0.f};
#pragma unroll
    for (int dy = 0; dy < 3; dy++) {
        const float* row = &t[(rr + dy) * 132 + c8];  // LDS idx c8 == image col c8-1
        float r[12] __attribute__((aligned(16)));
        *(f32x4*)&r[0] = *(const f32x4*)row;
        *(f32x4*)&r[4] = *(const f32x4*)(row + 4);
        *(f32x4*)&r[8] = *(const f32x4*)(row + 8);
        const float w0 = w[dy * 3], w1 = w[dy * 3 + 1], w2 = w[dy * 3 + 2];
#pragma unroll
        for (int j = 0; j < 8; j++) o[j] += w0 * r[j] + w1 * r[j + 1] + w2 * r[j + 2];
    }
    u16 ob[8] __attribute__((aligned(16)));
#pragma unroll
    for (int j = 0; j < 8; j++) ob[j] = f2b(o[j]);
    *(bf16x8*)&op[(long long)(r0 + rr) * 128 + c8] = *(const bf16x8*)ob;
}

// S[bh][48][48] += q.k^T ; norms[bh][96] += diag(q.q^T), diag(k.k^T)
__global__ __launch_bounds__(256) void attn_scores(
    const u16* __restrict__ qk, float* __restrict__ S, float* __restrict__ norms,
    int bh0)
{
    const int tid = threadIdx.x, lane = tid & 63, wid = tid >> 6;
    const int kc = blockIdx.x, head = blockIdx.y;
    const long long bz = blockIdx.z;
    const u16* q = qk + bz * (2LL * CD * HW) + (long long)head * 48 * HW;
    const u16* k = q + (long long)CD * HW;
    const int lr = lane & 15, quad = lane >> 4;

    f32x4 sc[3][3], sq[3], sk[3];
#pragma unroll
    for (int i = 0; i < 3; i++) {
#pragma unroll
        for (int j = 0; j < 3; j++) sc[i][j] = (f32x4){0.f, 0.f, 0.f, 0.f};
        sq[i] = (f32x4){0.f, 0.f, 0.f, 0.f};
        sk[i] = (f32x4){0.f, 0.f, 0.f, 0.f};
    }
    const int n0 = kc * 1024 + wid * 256;
#pragma unroll 2
    for (int s = 0; s < 8; s++) {
        const int n = n0 + s * 32 + quad * 8;
        bf16x8 aq[3], ak[3];
#pragma unroll
        for (int t3 = 0; t3 < 3; t3++) {
            aq[t3] = *(const bf16x8*)(q + (long long)(t3 * 16 + lr) * HW + n);
            ak[t3] = *(const bf16x8*)(k + (long long)(t3 * 16 + lr) * HW + n);
        }
#pragma unroll
        for (int mt = 0; mt < 3; mt++)
#pragma unroll
            for (int nt = 0; nt < 3; nt++)
                sc[mt][nt] = __builtin_amdgcn_mfma_f32_16x16x32_bf16(aq[mt], ak[nt], sc[mt][nt], 0, 0, 0);
#pragma unroll
        for (int t3 = 0; t3 < 3; t3++) {
            sq[t3] = __builtin_amdgcn_mfma_f32_16x16x32_bf16(aq[t3], aq[t3], sq[t3], 0, 0, 0);
            sk[t3] = __builtin_amdgcn_mfma_f32_16x16x32_bf16(ak[t3], ak[t3], sk[t3], 0, 0, 0);
        }
    }
    __shared__ float sS[2304];
    __shared__ float snq[48], snk[48];
    for (int i = tid; i < 2304; i += 256) sS[i] = 0.f;
    if (tid < 48) { snq[tid] = 0.f; snk[tid] = 0.f; }
    __syncthreads();
#pragma unroll
    for (int mt = 0; mt < 3; mt++)
#pragma unroll
        for (int nt = 0; nt < 3; nt++)
#pragma unroll
            for (int r = 0; r < 4; r++)
                atomicAdd(&sS[(mt * 16 + quad * 4 + r) * 48 + nt * 16 + lr], sc[mt][nt][r]);
#pragma unroll
    for (int t3 = 0; t3 < 3; t3++)
#pragma unroll
        for (int r = 0; r < 4; r++) {
            int rw = quad * 4 + r;
            if (rw == lr) {
                atomicAdd(&snq[t3 * 16 + rw], sq[t3][r]);
                atomicAdd(&snk[t3 * 16 + rw], sk[t3][r]);
            }
        }
    __syncthreads();
    const int bh = bh0 + (int)bz * 4 + head;
    float* Sg = S + (long long)bh * 2304;
    for (int i = tid; i < 2304; i += 256) atomicAdd(&Sg[i], sS[i]);
    float* ng = norms + bh * 96;
    if (tid < 48) atomicAdd(&ng[tid], snq[tid]);
    else if (tid < 96) atomicAdd(&ng[tid], snk[tid - 48]);
}

// Fused softmax + projection. Each block (ob, b): compute the batch's full
// 192-row softmax (1 row/thread, redundant across the 4 ob-blocks — cheap)
// into sA, then MmF[b] = W_proj . blockdiag(attn) in A-fragment layout.
__global__ __launch_bounds__(256) void mproj_sm(
    const float* __restrict__ wproj, const float* __restrict__ S,
    const float* __restrict__ norms, const float* __restrict__ temp,
    u16* __restrict__ Mm, int b0)
{
    const int ob = blockIdx.x, b = b0 + blockIdx.y, tid = threadIdx.x;
    __shared__ float sA[9216];
    if (tid < 192) {
        const int h = tid / 48, r = tid - h * 48;
        const int bh = b * 4 + h;
        const float tv = temp[h];
        const float* Sg = S + (long long)bh * 2304;
        const float* ng = norms + bh * 96;
        const float nq = fmaxf(sqrtf(ng[r]), 1e-12f);
        float lg[48];
        float mx = -1e30f;
#pragma unroll
        for (int d = 0; d < 48; d++) {
            float nk = fmaxf(sqrtf(ng[48 + d]), 1e-12f);
            float v = Sg[r * 48 + d] * tv / (nq * nk);
            lg[d] = v; mx = fmaxf(mx, v);
        }
        float sum = 0.f;
#pragma unroll
        for (int d = 0; d < 48; d++) { float e = __expf(lg[d] - mx); lg[d] = e; sum += e; }
        const float inv = 1.f / sum;
#pragma unroll
        for (int d = 0; d < 48; d++) sA[h * 2304 + r * 48 + d] = lg[d] * inv;
    }
    __syncthreads();
    for (int i = tid; i < 48 * 192; i += 256) {
        int o = ob * 48 + i / 192;
        int cc = i % 192;
        int h = cc / 48, d = cc - h * 48;
        const float* wr = wproj + o * 192 + h * 48;
        const float* ar = &sA[h * 2304 + d];
        float acc = 0.f;
        for (int c = 0; c < 48; c++) acc += wr[c] * ar[c * 48];
        // frag-layout store: F = (o>>6)*24 + ((o>>4)&3)*6 + (cc>>5)
        int fi = (o >> 6) * 24 + ((o >> 4) & 3) * 6 + (cc >> 5);
        int lanei = ((cc >> 3) & 3) * 16 + (o & 15);
        Mm[(long long)b * 49152 + (long long)fi * 512 + lanei * 8 + (cc & 7)] = f2b(acc);
    }
}

extern "C" void kernel_launch(void* const* d_in, const int* in_sizes, int n_in,
                              void* d_out, int out_size, void* d_ws, size_t ws_size,
                              hipStream_t stream)
{
    const float* x     = (const float*)d_in[0];
    const float* wqkv  = (const float*)d_in[1];
    const float* wdw   = (const float*)d_in[2];
    const float* temp  = (const float*)d_in[3];
    const float* wproj = (const float*)d_in[4];
    float* out = (float*)d_out;
    char* ws = (char*)d_ws;
    const long long CHW = (long long)CD * HW;

    if (ws_size < 2097152ULL + 31457280ULL) {  // G=1 floor (proved present)
        fill_f32<<<2048, 256, 0, stream>>>(out, out_size, 100.0f);
        return;
    }
    int G = 8;
    while (G > 1 && (unsigned long long)(2097152ULL + (unsigned long long)G * 31457280ULL) > (unsigned long long)ws_size)
        G >>= 1;

    float* S      = (float*)ws;                // 32*2304 f32
    float* norms  = (float*)(ws + 294912);     // 32*96 f32
    u16*   MmF    = (u16*)(ws + 602112);       // 8 * 96 frags * 512 u16
    u16*   wqkvF  = (u16*)(ws + 1388544);      // 240 frags * 512 u16
    u16* region1  = (u16*)(ws + 2097152);      // G*2CHW bf16 (qk_post)
    u16* qkv_pre  = region1 + (long long)G * 2 * CHW;  // G*3CHW bf16

    zerof<<<300, 256, 0, stream>>>(S, 76800);  // S + norms contiguous
    afrag_prep<<<60, 256, 0, stream>>>(wqkv, wqkvF, O3, 240);

    for (int g0 = 0; g0 < 8; g0 += G) {
        // qkv_pre = Wqkv . x  (B = x fp32 [c][p], transposed+cvt in staging)
        gemm_tn<true, false, 18><<<dim3(128, 1, G), 256, 0, stream>>>(
            wqkvF, x + (long long)g0 * CHW, qkv_pre, 0LL, CHW, 3LL * CHW);
        dwconv2<<<dim3(8, 384, G), 256, 0, stream>>>(
            qkv_pre, wdw, region1, 3LL * CHW, 2LL * CHW, 0);
        dwconv2<<<dim3(8, 192, G), 256, 0, stream>>>(
            qkv_pre + 2LL * CHW, wdw, qkv_pre, 3LL * CHW, 3LL * CHW, 384);
        attn_scores<<<dim3(16, 4, G), 256, 0, stream>>>(region1, S, norms, g0 * 4);
        mproj_sm<<<dim3(4, G), 256, 0, stream>>>(wproj, S, norms, temp, MmF, g0);
        // out = MmF . v_post  (B = qkv_pre ch[0,192) bf16 [c][p])
        gemm_tn<false, true, 6><<<dim3(128, 1, G), 256, 0, stream>>>(
            MmF + (long long)g0 * 49152, qkv_pre, out + (long long)g0 * CHW,
            49152LL, 3LL * CHW, CHW);
    }
}